// Round 3
// baseline (284.006 us; speedup 1.0000x reference)
//
#include <hip/hip_runtime.h>

// IndRNN 2-layer diagonal recurrence via chunked associative scan.
//   Per chain (b,h): h[t] = relu(x[t] + w*h[t-1]).
//   Maps f(h)=relu(c+w*h) on h>=0 compose closed-form: f(h)=max(b, a+s*h),
//     a' = c + w*a ; b' = max(0, c + w*b) ; s = w^len.
// 3 passes: L1 triples -> LDS scan -> exact L1 + L2 triples -> LDS scan ->
// exact L1+L2 + store. x read 3x (passes 2,3 expected L3-hot), out written once.
//
// Geometry: 32 chains x 32 chunks per 1024-thread block; 512 blocks ->
// 2 blocks/CU = 32 waves/CU (vs 1 wave/CU in the sequential kernel).

#define TSTEPS 2048
#define BATCH  32
#define HID    512
#define BH     (BATCH * HID)   /* 16384 chains */
#define CH     32              /* chains per block  */
#define NC     32              /* time chunks       */
#define CL     (TSTEPS / NC)   /* 64 steps per chunk */

__global__ __launch_bounds__(1024, 8) void indrnn_scan_kernel(
    const float* __restrict__ x,
    const float* __restrict__ w_hh,
    const float* __restrict__ h0,
    float* __restrict__ out) {
  const int tid = threadIdx.x;
  const int chl = tid & (CH - 1);   // chain-local 0..31
  const int ci  = tid >> 5;         // chunk index 0..31
  const int c   = blockIdx.x * CH + chl;
  const int hid = c & (HID - 1);

  const float w1 = w_hh[hid];
  const float w2 = w_hh[HID + hid];
  // s = w^CL, CL=64=2^6: 6 squarings
  float s1 = w1, s2 = w2;
#pragma unroll
  for (int i = 0; i < 6; ++i) { s1 *= s1; s2 *= s2; }

  __shared__ float A[NC][CH], B[NC][CH], HS1[NC][CH], HS2[NC][CH];

  const size_t base = (size_t)ci * CL * BH + c;
  const float* xp = x + base;
  float*       op = out + base;

  // ---- pass 1: layer-1 chunk triple (a1,b1) ----
  float a1 = 0.f, b1 = 0.f;
#pragma unroll 4
  for (int s = 0; s < CL; ++s) {
    float xv = xp[(size_t)s * BH];
    a1 = fmaf(w1, a1, xv);
    b1 = fmaxf(fmaf(w1, b1, xv), 0.f);
  }
  A[ci][chl] = a1;
  B[ci][chl] = b1;
  __syncthreads();

  // ---- scan layer 1 over chunks (wave-0 lanes, one per chain) ----
  if (ci == 0) {
    float h = h0[c];
#pragma unroll
    for (int k = 0; k < NC; ++k) {
      HS1[k][chl] = h;
      h = fmaxf(fmaf(s1, h, A[k][chl]), B[k][chl]);
    }
  }
  __syncthreads();

  // ---- pass 2: exact layer 1, build layer-2 triple ----
  float h1 = HS1[ci][chl];
  float a2 = 0.f, b2 = 0.f;
#pragma unroll 4
  for (int s = 0; s < CL; ++s) {
    float xv = xp[(size_t)s * BH];
    h1 = fmaxf(fmaf(w1, h1, xv), 0.f);
    a2 = fmaf(w2, a2, h1);
    b2 = fmaxf(fmaf(w2, b2, h1), 0.f);
  }
  __syncthreads();   // layer-1 scan's reads of A,B are done; safe to reuse
  A[ci][chl] = a2;
  B[ci][chl] = b2;
  __syncthreads();

  // ---- scan layer 2 over chunks ----
  if (ci == 0) {
    float h = h0[BH + c];
#pragma unroll
    for (int k = 0; k < NC; ++k) {
      HS2[k][chl] = h;
      h = fmaxf(fmaf(s2, h, A[k][chl]), B[k][chl]);
    }
  }
  __syncthreads();

  // ---- pass 3: exact both layers, store ----
  h1 = HS1[ci][chl];
  float h2 = HS2[ci][chl];
#pragma unroll 4
  for (int s = 0; s < CL; ++s) {
    float xv = xp[(size_t)s * BH];
    h1 = fmaxf(fmaf(w1, h1, xv), 0.f);
    h2 = fmaxf(fmaf(w2, h2, h1), 0.f);
    op[(size_t)s * BH] = h2;
  }
}

extern "C" void kernel_launch(void* const* d_in, const int* in_sizes, int n_in,
                              void* d_out, int out_size, void* d_ws, size_t ws_size,
                              hipStream_t stream) {
  const float* x    = (const float*)d_in[0];
  const float* w_hh = (const float*)d_in[1];
  const float* h0   = (const float*)d_in[2];
  float* out        = (float*)d_out;

  dim3 grid(BH / CH);     // 512 blocks
  dim3 block(CH * NC);    // 1024 threads
  hipLaunchKernelGGL(indrnn_scan_kernel, grid, block, 0, stream,
                     x, w_hh, h0, out);
}